// Round 5
// baseline (183.472 us; speedup 1.0000x reference)
//
#include <hip/hip_runtime.h>

// CapsNet dynamic routing: ONE WAVE PER BATCH ELEMENT, no multi-wave barriers.
// u = x@W never materialized (linear in x):
//   s[j] = (sum_i c[j,i] x[i,:]) @ W_j      (PA: MFMA, A=c bf16 LDS, B=x global)
//   dblog[j,i] = x[i,:] . (W_j @ o[j])      (PB: MFMA, A=wt in regs, B=x global)
// blog lives in 32 MFMA C-fragments (128 VGPR) across rounds; c is the only
// LDS table (bf16 [16][520], conflict-free b128: group=(l15+lg4)%8, 8 lanes ea).
// o moves lane->lane via shfl_xor; wt is built directly in A-frag layout.
// Grid 512 x 64: 2 waves/CU, all co-resident, chain ~15K cycles.

#define NJ 10
#define CT_STRIDE 520     // bf16 per row of cT; 1040 B = 65*16 (16B-aligned rows)
#define Y_STRIDE 36       // f32 per row of yL; 144 B rows, group js*9%8 bijective

typedef __attribute__((ext_vector_type(8))) short short8;
typedef __attribute__((ext_vector_type(4))) float f32x4;

__device__ __forceinline__ unsigned cvt_pk_bf16(float lo, float hi) {
    unsigned d;
    asm volatile("v_cvt_pk_bf16_f32 %0, %1, %2" : "=v"(d) : "v"(lo), "v"(hi));
    return d;
}
__device__ __forceinline__ short f2bf(float f) {   // RNE f32->bf16
    unsigned u = __float_as_uint(f);
    return (short)((u + 0x7FFFu + ((u >> 16) & 1u)) >> 16);
}

__global__ __launch_bounds__(64, 1) void capsnet_kernel(
    const float* __restrict__ x, const float* __restrict__ W,
    float* __restrict__ out)
{
    __shared__ __attribute__((aligned(16))) short cT[16 * CT_STRIDE]; // 16,640 B
    __shared__ __attribute__((aligned(16))) float yL[16 * Y_STRIDE];  //  2,304 B

    const int lane = threadIdx.x;          // 0..63
    const int b    = blockIdx.x;
    const int l15  = lane & 15;
    const int lg4  = lane >> 4;            // quad 0..3
    const bool jok = (l15 < NJ);
    const int js   = jok ? l15 : (NJ - 1); // clamped j for safe W addressing
    const float* xg = x + (size_t)b * (512 * 32);

    // ---- r0: colsum[k] -> y0 = 0.1*colsum (c uniform = 1/J), f32-exact ----
    {
        const float4* xg4 = reinterpret_cast<const float4*>(xg);
        float4 s4 = make_float4(0.f, 0.f, 0.f, 0.f);
        #pragma unroll 8
        for (int q = 0; q < 64; ++q) {     // lane covers k-quad (lane&7), rows (lane>>3)+8q
            const float4 v = xg4[lane + (q << 6)];
            s4.x += v.x; s4.y += v.y; s4.z += v.z; s4.w += v.w;
        }
        #pragma unroll
        for (int msk = 8; msk <= 32; msk <<= 1) {
            s4.x += __shfl_xor(s4.x, msk); s4.y += __shfl_xor(s4.y, msk);
            s4.z += __shfl_xor(s4.z, msk); s4.w += __shfl_xor(s4.w, msk);
        }
        if (lane < 8) {
            float4 y0 = make_float4(0.1f * s4.x, 0.1f * s4.y, 0.1f * s4.z, 0.1f * s4.w);
            #pragma unroll
            for (int j = 0; j < NJ; ++j)
                *reinterpret_cast<float4*>(&yL[j * Y_STRIDE + (lane << 2)]) = y0;
        }
    }
    __syncthreads();   // single-wave: cheap; orders LDS write->cross-lane read

    f32x4 blogA[32];                       // blogT[j=lg4*4+rr][i=T*16+l15], persists
    #pragma unroll
    for (int T = 0; T < 32; ++T) blogA[T] = (f32x4){0.f, 0.f, 0.f, 0.f};

    short8 wfrag;                          // wt A-frag: wt[j=l15][k=lg4*8+q]
    float4 o4;                             // o[js][d=lg4*4..+3]
    float lgt = 0.f;

    for (int r = 0; r < 3; ++r) {
        if (r > 0) {
            // ===== PB: blogA[T] += wt(A) @ x(B);  then softmax_j -> cT =====
            #pragma unroll
            for (int T = 0; T < 32; ++T) {
                const float* xrow = xg + (((T << 4) + l15) << 5) + (lg4 << 3);
                const float4 a0 = *reinterpret_cast<const float4*>(xrow);
                const float4 a1 = *reinterpret_cast<const float4*>(xrow + 4);
                union { unsigned u[4]; short8 s8; } cv;
                cv.u[0] = cvt_pk_bf16(a0.x, a0.y);
                cv.u[1] = cvt_pk_bf16(a0.z, a0.w);
                cv.u[2] = cvt_pk_bf16(a1.x, a1.y);
                cv.u[3] = cvt_pk_bf16(a1.z, a1.w);
                blogA[T] = __builtin_amdgcn_mfma_f32_16x16x32_bf16(wfrag, cv.s8, blogA[T], 0, 0, 0);
            }
            #pragma unroll
            for (int T = 0; T < 32; ++T) {
                const f32x4 bv = blogA[T];
                const int jb = lg4 << 2;
                const float v0 = (jb + 0 < NJ) ? bv[0] : -1e30f;
                const float v1 = (jb + 1 < NJ) ? bv[1] : -1e30f;
                const float v2 = (jb + 2 < NJ) ? bv[2] : -1e30f;
                const float v3 = (jb + 3 < NJ) ? bv[3] : -1e30f;
                float m = fmaxf(fmaxf(v0, v1), fmaxf(v2, v3));
                m = fmaxf(m, __shfl_xor(m, 16));
                m = fmaxf(m, __shfl_xor(m, 32));
                const float e0 = __expf(v0 - m), e1 = __expf(v1 - m);
                const float e2 = __expf(v2 - m), e3 = __expf(v3 - m);
                float ssum = e0 + e1 + e2 + e3;
                ssum += __shfl_xor(ssum, 16);
                ssum += __shfl_xor(ssum, 32);
                const float inv = 1.f / ssum;
                const int i = (T << 4) + l15;
                cT[(jb + 0) * CT_STRIDE + i] = f2bf(e0 * inv);
                cT[(jb + 1) * CT_STRIDE + i] = f2bf(e1 * inv);
                cT[(jb + 2) * CT_STRIDE + i] = f2bf(e2 * inv);
                cT[(jb + 3) * CT_STRIDE + i] = f2bf(e3 * inv);
            }
            __syncthreads();

            // ===== PA: y[j][k] = cT(A) @ x(B), K=512, 2 n-tiles =====
            {
                f32x4 yf0 = (f32x4){0.f, 0.f, 0.f, 0.f};
                f32x4 yf1 = (f32x4){0.f, 0.f, 0.f, 0.f};
                #pragma unroll
                for (int s = 0; s < 16; ++s) {
                    const short8 ca = *reinterpret_cast<const short8*>(
                        &cT[l15 * CT_STRIDE + (s << 5) + (lg4 << 3)]);
                    const float* xb = xg + (((s << 5) + (lg4 << 3)) << 5) + l15;
                    union { unsigned u[4]; short8 s8; } b0, b1;
                    b0.u[0] = cvt_pk_bf16(xb[0 * 32], xb[1 * 32]);
                    b0.u[1] = cvt_pk_bf16(xb[2 * 32], xb[3 * 32]);
                    b0.u[2] = cvt_pk_bf16(xb[4 * 32], xb[5 * 32]);
                    b0.u[3] = cvt_pk_bf16(xb[6 * 32], xb[7 * 32]);
                    b1.u[0] = cvt_pk_bf16(xb[0 * 32 + 16], xb[1 * 32 + 16]);
                    b1.u[1] = cvt_pk_bf16(xb[2 * 32 + 16], xb[3 * 32 + 16]);
                    b1.u[2] = cvt_pk_bf16(xb[4 * 32 + 16], xb[5 * 32 + 16]);
                    b1.u[3] = cvt_pk_bf16(xb[6 * 32 + 16], xb[7 * 32 + 16]);
                    yf0 = __builtin_amdgcn_mfma_f32_16x16x32_bf16(ca, b0.s8, yf0, 0, 0, 0);
                    yf1 = __builtin_amdgcn_mfma_f32_16x16x32_bf16(ca, b1.s8, yf1, 0, 0, 0);
                }
                #pragma unroll
                for (int rr = 0; rr < 4; ++rr) {
                    yL[((lg4 << 2) + rr) * Y_STRIDE + l15]      = yf0[rr];
                    yL[((lg4 << 2) + rr) * Y_STRIDE + 16 + l15] = yf1[rr];
                }
            }
            __syncthreads();
        }

        // ===== S: s[js][d] = y[js]@W_js (d=lg4*4..+3), squash -> o4 =====
        {
            float4 sa = make_float4(0.f, 0.f, 0.f, 0.f);
            #pragma unroll
            for (int k4 = 0; k4 < 8; ++k4) {
                const float4 y4 = *reinterpret_cast<const float4*>(&yL[js * Y_STRIDE + (k4 << 2)]);
                const float* wp = W + (k4 << 2) * 160 + js * 16 + (lg4 << 2);
                const float4 w0 = *reinterpret_cast<const float4*>(wp);
                const float4 w1 = *reinterpret_cast<const float4*>(wp + 160);
                const float4 w2 = *reinterpret_cast<const float4*>(wp + 320);
                const float4 w3 = *reinterpret_cast<const float4*>(wp + 480);
                sa.x = fmaf(y4.x, w0.x, fmaf(y4.y, w1.x, fmaf(y4.z, w2.x, fmaf(y4.w, w3.x, sa.x))));
                sa.y = fmaf(y4.x, w0.y, fmaf(y4.y, w1.y, fmaf(y4.z, w2.y, fmaf(y4.w, w3.y, sa.y))));
                sa.z = fmaf(y4.x, w0.z, fmaf(y4.y, w1.z, fmaf(y4.z, w2.z, fmaf(y4.w, w3.z, sa.z))));
                sa.w = fmaf(y4.x, w0.w, fmaf(y4.y, w1.w, fmaf(y4.z, w2.w, fmaf(y4.w, w3.w, sa.w))));
            }
            float sq = sa.x * sa.x + sa.y * sa.y + sa.z * sa.z + sa.w * sa.w;
            sq += __shfl_xor(sq, 16);
            sq += __shfl_xor(sq, 32);
            const float scale = (sq / (1.f + sq)) / sqrtf(sq + 1e-7f);
            o4.x = sa.x * scale; o4.y = sa.y * scale;
            o4.z = sa.z * scale; o4.w = sa.w * scale;
        }

        if (r == 2) {
            lgt = o4.x + o4.y + o4.z + o4.w;          // sum over own d-quad
            lgt += __shfl_xor(lgt, 16);
            lgt += __shfl_xor(lgt, 32);               // logits[js] on all quads
            break;
        }

        // ===== WT: wt[js][k=lg4*8+q] = sum_d W[k][js*16+d]*o[js][d] -> wfrag =====
        {
            float wtv[8];
            #pragma unroll
            for (int kk = 0; kk < 8; ++kk) wtv[kk] = 0.f;
            #pragma unroll
            for (int s_ = 0; s_ < 4; ++s_) {          // gather o-quads from sibling lanes
                const float q0 = (s_ == 0) ? o4.x : __shfl_xor(o4.x, s_ << 4);
                const float q1 = (s_ == 0) ? o4.y : __shfl_xor(o4.y, s_ << 4);
                const float q2 = (s_ == 0) ? o4.z : __shfl_xor(o4.z, s_ << 4);
                const float q3 = (s_ == 0) ? o4.w : __shfl_xor(o4.w, s_ << 4);
                const int dbase = (lg4 ^ s_) << 2;    // that quad's d-range
                const float* wp = W + (lg4 << 3) * 160 + js * 16 + dbase;
                #pragma unroll
                for (int kk = 0; kk < 8; ++kk) {
                    const float4 wv = *reinterpret_cast<const float4*>(wp + kk * 160);
                    wtv[kk] += q0 * wv.x + q1 * wv.y + q2 * wv.z + q3 * wv.w;
                }
            }
            const float z = jok ? 1.f : 0.f;          // zero pad-j rows of A
            union { unsigned u[4]; short8 s8; } wc;
            wc.u[0] = cvt_pk_bf16(wtv[0] * z, wtv[1] * z);
            wc.u[1] = cvt_pk_bf16(wtv[2] * z, wtv[3] * z);
            wc.u[2] = cvt_pk_bf16(wtv[4] * z, wtv[5] * z);
            wc.u[3] = cvt_pk_bf16(wtv[6] * z, wtv[7] * z);
            wfrag = wc.s8;
        }
    }

    // ---- final softmax over j (within 16-lane group), write out[b][0..9] ----
    {
        const float v = jok ? lgt : -1e30f;
        float m = v;
        m = fmaxf(m, __shfl_xor(m, 1));
        m = fmaxf(m, __shfl_xor(m, 2));
        m = fmaxf(m, __shfl_xor(m, 4));
        m = fmaxf(m, __shfl_xor(m, 8));
        const float e = jok ? __expf(lgt - m) : 0.f;
        float ssum = e;
        ssum += __shfl_xor(ssum, 1);
        ssum += __shfl_xor(ssum, 2);
        ssum += __shfl_xor(ssum, 4);
        ssum += __shfl_xor(ssum, 8);
        if (lane < NJ) out[b * NJ + lane] = e / ssum;
    }
}

extern "C" void kernel_launch(void* const* d_in, const int* in_sizes, int n_in,
                              void* d_out, int out_size, void* d_ws, size_t ws_size,
                              hipStream_t stream) {
    (void)in_sizes; (void)n_in; (void)d_ws; (void)ws_size; (void)out_size;
    const float* x = (const float*)d_in[0];
    const float* W = (const float*)d_in[1];
    float* out = (float*)d_out;
    hipLaunchKernelGGL(capsnet_kernel, dim3(512), dim3(64), 0, stream, x, W, out);
}

// Round 7
// 25.192 us; speedup vs baseline: 7.2830x; 7.2830x over previous
//
#include <hip/hip_runtime.h>

// CapsNet dynamic routing, fused, MFMA, 4 waves/block, 1 batch element/block.
// u = x@W never materialized (linear in x):
//   PA: y[j][k] = c(A) @ x(B)           PB: blogT[j][i] += wt(A) @ xT(B)
// x's PB-B and PA-B fragments are ROUND-INVARIANT -> bf16 register caches
// (xA[8], xB[4][2]); zero global x reads after staging. blog persists in 8
// MFMA C-fragments. LDS: cT bf16 [16][520] (1040B rows, 16B-aligned, <=2-way
// banks), wtb bf16 [16][40], ypart/yb f32. R7 fix: CT_STRIDE 264 -> 520
// (rows must hold 512 i's; 264 made rows overlap + OOB -> absmax 0.36).
// Grid 512x256 = 2 blocks/CU resident.

#define NJ 10
#define NT 256
#define CT_STRIDE 520   // shorts/row of cT: 1040 B = 65*16
#define WT_STRIDE 40    // shorts/row of wtb: 80 B = 5*16
#define Y_STRIDE 36     // f32/row of yb: 144 B
#define YP_WS 576       // f32 per ypart wave slab (16*36)

typedef __attribute__((ext_vector_type(8))) short short8;
typedef __attribute__((ext_vector_type(4))) float f32x4;

__device__ __forceinline__ unsigned cvt_pk_bf16(float lo, float hi) {
    unsigned d;
    asm volatile("v_cvt_pk_bf16_f32 %0, %1, %2" : "=v"(d) : "v"(lo), "v"(hi));
    return d;
}
__device__ __forceinline__ short f2bf(float f) {   // RNE f32->bf16
    unsigned u = __float_as_uint(f);
    return (short)((u + 0x7FFFu + ((u >> 16) & 1u)) >> 16);
}

__global__ __launch_bounds__(NT, 2) void capsnet_kernel(
    const float* __restrict__ x, const float* __restrict__ W,
    float* __restrict__ out)
{
    __shared__ __attribute__((aligned(16))) short cT[16 * CT_STRIDE];  // 16,640 B
    __shared__ __attribute__((aligned(16))) short wtb[16 * WT_STRIDE]; //  1,280 B
    __shared__ __attribute__((aligned(16))) float ypart[4 * YP_WS];    //  9,216 B
    __shared__ __attribute__((aligned(16))) float yb[16 * Y_STRIDE];   //  2,304 B
    __shared__ __attribute__((aligned(16))) float ob[160];
    __shared__ float lgt[16];

    const int tid  = threadIdx.x;
    const int b    = blockIdx.x;
    const int lane = tid & 63;
    const int w    = tid >> 6;            // wave 0..3
    const int l15  = lane & 15;
    const int lg4  = lane >> 4;           // quad 0..3
    const float* xg = x + (size_t)b * (512 * 32);

    // ---- stage 1: colsum partials (coalesced full read of x) ----
    {
        float4* scr = reinterpret_cast<float4*>(ypart);   // 4 KB scratch
        const float4* xg4 = reinterpret_cast<const float4*>(xg);
        float4 s4 = make_float4(0.f, 0.f, 0.f, 0.f);
        #pragma unroll
        for (int q = 0; q < 16; ++q) {    // thread's k-quad = 4*(tid&7), rows (tid>>3)+32q
            const float4 v = xg4[tid + (q << 8)];
            s4.x += v.x; s4.y += v.y; s4.z += v.z; s4.w += v.w;
        }
        scr[tid] = s4;
    }

    // ---- stage 2: round-invariant x fragments into registers (bf16) ----
    short8 xA[8];        // PB B-frag: x[w*128+T*16+l15][lg4*8..+7]
    #pragma unroll
    for (int T = 0; T < 8; ++T) {
        const float* p = xg + ((w << 7) + (T << 4) + l15) * 32 + (lg4 << 3);
        const float4 a0 = *reinterpret_cast<const float4*>(p);
        const float4 a1 = *reinterpret_cast<const float4*>(p + 4);
        union { unsigned u[4]; short8 s8; } cv;
        cv.u[0] = cvt_pk_bf16(a0.x, a0.y);
        cv.u[1] = cvt_pk_bf16(a0.z, a0.w);
        cv.u[2] = cvt_pk_bf16(a1.x, a1.y);
        cv.u[3] = cvt_pk_bf16(a1.z, a1.w);
        xA[T] = cv.s8;
    }
    short8 xB[4][2];     // PA B-frag: B[i=(4w+s)*32+lg4*8+q][k=l15+16t] = x[i][k]
    #pragma unroll
    for (int s = 0; s < 4; ++s) {
        const int ib = ((w << 2) + s) << 5;
        #pragma unroll
        for (int t = 0; t < 2; ++t) {
            const float* p = xg + (ib + (lg4 << 3)) * 32 + l15 + (t << 4);
            union { unsigned u[4]; short8 s8; } cv;
            cv.u[0] = cvt_pk_bf16(p[0 * 32], p[1 * 32]);
            cv.u[1] = cvt_pk_bf16(p[2 * 32], p[3 * 32]);
            cv.u[2] = cvt_pk_bf16(p[4 * 32], p[5 * 32]);
            cv.u[3] = cvt_pk_bf16(p[6 * 32], p[7 * 32]);
            xB[s][t] = cv.s8;
        }
    }
    __syncthreads();

    // ---- y0 = 0.1 * colsum (c uniform = 1/J), f32-exact ----
    if (tid < 8) {
        const float4* scr = reinterpret_cast<const float4*>(ypart);
        float4 s = make_float4(0.f, 0.f, 0.f, 0.f);
        #pragma unroll
        for (int m = 0; m < 32; ++m) {
            const float4 v = scr[tid + (m << 3)];
            s.x += v.x; s.y += v.y; s.z += v.z; s.w += v.w;
        }
        s.x *= 0.1f; s.y *= 0.1f; s.z *= 0.1f; s.w *= 0.1f;
        #pragma unroll
        for (int j = 0; j < NJ; ++j)
            *reinterpret_cast<float4*>(&yb[j * Y_STRIDE + (tid << 2)]) = s;
    }
    __syncthreads();

    f32x4 blogA[8];      // blogT[j=lg4*4+rr][i=w*128+T*16+l15], persists all rounds
    #pragma unroll
    for (int T = 0; T < 8; ++T) blogA[T] = (f32x4){0.f, 0.f, 0.f, 0.f};

    for (int r = 0; r < 3; ++r) {
        // ===== S: s[j][d] = y[j] @ W_j(:,d); squash (r==2: logits) =====
        if (tid < 160) {
            const int j = tid >> 4, d = tid & 15;
            float s = 0.f;
            #pragma unroll
            for (int k4 = 0; k4 < 8; ++k4) {
                const float4 y4 = *reinterpret_cast<const float4*>(&yb[j * Y_STRIDE + (k4 << 2)]);
                const float* wp = W + (k4 << 2) * 160 + (j << 4) + d;
                s = fmaf(y4.x, wp[0],   s);
                s = fmaf(y4.y, wp[160], s);
                s = fmaf(y4.z, wp[320], s);
                s = fmaf(y4.w, wp[480], s);
            }
            float sq = s * s;
            sq += __shfl_xor(sq, 1); sq += __shfl_xor(sq, 2);
            sq += __shfl_xor(sq, 4); sq += __shfl_xor(sq, 8);
            const float scale = (sq / (1.f + sq)) / sqrtf(sq + 1e-7f);
            const float o_ = s * scale;
            if (r < 2) {
                ob[tid] = o_;
            } else {
                float ss = o_;
                ss += __shfl_xor(ss, 1); ss += __shfl_xor(ss, 2);
                ss += __shfl_xor(ss, 4); ss += __shfl_xor(ss, 8);
                if (d == 0) lgt[j] = ss;
            }
        }
        __syncthreads();
        if (r == 2) break;

        // ===== WT: wtb[j][k] = W_j-row(k) . o[j], rows j>=10 zeroed =====
        #pragma unroll
        for (int e = tid; e < 512; e += NT) {
            const int j = e >> 5, kk = e & 31;
            const int jc = (j < NJ) ? j : (NJ - 1);
            const float zj = (j < NJ) ? 1.f : 0.f;
            const float4* W4 = reinterpret_cast<const float4*>(W + kk * 160 + (jc << 4));
            const float4* o4 = reinterpret_cast<const float4*>(&ob[jc << 4]);
            float s = 0.f;
            #pragma unroll
            for (int q = 0; q < 4; ++q) {
                const float4 wv = W4[q]; const float4 ov = o4[q];
                s += wv.x * ov.x + wv.y * ov.y + wv.z * ov.z + wv.w * ov.w;
            }
            wtb[j * WT_STRIDE + kk] = f2bf(s * zj);
        }
        __syncthreads();

        // ===== PB: blogA[T] += wt(A) @ xT(B); softmax_j -> cT bf16 =====
        {
            const short8 wf = *reinterpret_cast<const short8*>(&wtb[l15 * WT_STRIDE + (lg4 << 3)]);
            #pragma unroll
            for (int T = 0; T < 8; ++T)
                blogA[T] = __builtin_amdgcn_mfma_f32_16x16x32_bf16(wf, xA[T], blogA[T], 0, 0, 0);
            const int jb = lg4 << 2;
            #pragma unroll
            for (int T = 0; T < 8; ++T) {
                const f32x4 bv = blogA[T];
                const float v0 = (jb + 0 < NJ) ? bv[0] : -1e30f;
                const float v1 = (jb + 1 < NJ) ? bv[1] : -1e30f;
                const float v2 = (jb + 2 < NJ) ? bv[2] : -1e30f;
                const float v3 = (jb + 3 < NJ) ? bv[3] : -1e30f;
                float m = fmaxf(fmaxf(v0, v1), fmaxf(v2, v3));
                m = fmaxf(m, __shfl_xor(m, 16));
                m = fmaxf(m, __shfl_xor(m, 32));
                const float e0 = __expf(v0 - m), e1 = __expf(v1 - m);
                const float e2 = __expf(v2 - m), e3 = __expf(v3 - m);
                float ssum = e0 + e1 + e2 + e3;
                ssum += __shfl_xor(ssum, 16);
                ssum += __shfl_xor(ssum, 32);
                const float inv = 1.f / ssum;
                const int i = (w << 7) + (T << 4) + l15;   // global i of this column
                cT[(jb + 0) * CT_STRIDE + i] = f2bf(e0 * inv);
                cT[(jb + 1) * CT_STRIDE + i] = f2bf(e1 * inv);
                cT[(jb + 2) * CT_STRIDE + i] = f2bf(e2 * inv);
                cT[(jb + 3) * CT_STRIDE + i] = f2bf(e3 * inv);
            }
        }
        __syncthreads();

        // ===== PA: y partials, wave w covers i in [w*128, w*128+128) =====
        {
            f32x4 yf0 = (f32x4){0.f, 0.f, 0.f, 0.f};
            f32x4 yf1 = (f32x4){0.f, 0.f, 0.f, 0.f};
            #pragma unroll
            for (int s = 0; s < 4; ++s) {
                const int sg = (w << 2) + s;
                const short8 ca = *reinterpret_cast<const short8*>(
                    &cT[l15 * CT_STRIDE + (sg << 5) + (lg4 << 3)]);
                yf0 = __builtin_amdgcn_mfma_f32_16x16x32_bf16(ca, xB[s][0], yf0, 0, 0, 0);
                yf1 = __builtin_amdgcn_mfma_f32_16x16x32_bf16(ca, xB[s][1], yf1, 0, 0, 0);
            }
            #pragma unroll
            for (int rr = 0; rr < 4; ++rr) {
                ypart[w * YP_WS + ((lg4 << 2) + rr) * Y_STRIDE + l15]      = yf0[rr];
                ypart[w * YP_WS + ((lg4 << 2) + rr) * Y_STRIDE + 16 + l15] = yf1[rr];
            }
        }
        __syncthreads();

        // ===== reduce 4-wave partials -> yb =====
        #pragma unroll
        for (int e = tid; e < 512; e += NT) {
            const int j = e >> 5, k = e & 31;
            float s = 0.f;
            #pragma unroll
            for (int ww = 0; ww < 4; ++ww) s += ypart[ww * YP_WS + j * Y_STRIDE + k];
            yb[j * Y_STRIDE + k] = s;
        }
        __syncthreads();
    }

    // ---- final softmax over j, write out[b][0..9] ----
    if (tid < NJ) {
        float m = -1e30f;
        #pragma unroll
        for (int j = 0; j < NJ; ++j) m = fmaxf(m, lgt[j]);
        float sum = 0.f;
        #pragma unroll
        for (int j = 0; j < NJ; ++j) sum += __expf(lgt[j] - m);
        out[b * NJ + tid] = __expf(lgt[tid] - m) / sum;
    }
}

extern "C" void kernel_launch(void* const* d_in, const int* in_sizes, int n_in,
                              void* d_out, int out_size, void* d_ws, size_t ws_size,
                              hipStream_t stream) {
    (void)in_sizes; (void)n_in; (void)d_ws; (void)ws_size; (void)out_size;
    const float* x = (const float*)d_in[0];
    const float* W = (const float*)d_in[1];
    float* out = (float*)d_out;
    hipLaunchKernelGGL(capsnet_kernel, dim3(512), dim3(NT), 0, stream, x, W, out);
}

// Round 8
// 24.439 us; speedup vs baseline: 7.5074x; 1.0308x over previous
//
#include <hip/hip_runtime.h>

// CapsNet dynamic routing, fused, MFMA, 8 waves/block, 1 batch element/block.
// u = x@W never materialized (linear in x):
//   PA: y[j][k] = c(A) @ x(B)           PB: blogT[j][i] += wt(A) @ xT(B)
// x fragments are ROUND-INVARIANT bf16 register caches (xA[4], xB[2][2]);
// zero global x reads after staging. blog persists in 4 MFMA C-fragments/wave.
// R8: 8 waves/element (was 4) -> 4096 waves total = 16/CU = 50% occupancy
// (grid fixes waves/CU; 4-wave blocks capped at 8/CU = 25%). PB: wave w owns
// i in [64w,64w+64); PA: wave w owns K-steps 2w,2w+1; 8-way ypart reduce.
// LDS ~40 KB -> 2 blocks/CU.

#define NJ 10
#define NT 512
#define CT_STRIDE 520   // shorts/row of cT: 1040 B = 65*16
#define WT_STRIDE 40    // shorts/row of wtb: 80 B = 5*16
#define Y_STRIDE 36     // f32/row of yb: 144 B
#define YP_WS 576       // f32 per ypart wave slab (16*36)

typedef __attribute__((ext_vector_type(8))) short short8;
typedef __attribute__((ext_vector_type(4))) float f32x4;

__device__ __forceinline__ unsigned cvt_pk_bf16(float lo, float hi) {
    unsigned d;
    asm volatile("v_cvt_pk_bf16_f32 %0, %1, %2" : "=v"(d) : "v"(lo), "v"(hi));
    return d;
}
__device__ __forceinline__ short f2bf(float f) {   // RNE f32->bf16
    unsigned u = __float_as_uint(f);
    return (short)((u + 0x7FFFu + ((u >> 16) & 1u)) >> 16);
}

__global__ __launch_bounds__(NT, 2) void capsnet_kernel(
    const float* __restrict__ x, const float* __restrict__ W,
    float* __restrict__ out)
{
    __shared__ __attribute__((aligned(16))) short cT[16 * CT_STRIDE];  // 16,640 B
    __shared__ __attribute__((aligned(16))) short wtb[16 * WT_STRIDE]; //  1,280 B
    __shared__ __attribute__((aligned(16))) float ypart[8 * YP_WS];    // 18,432 B
    __shared__ __attribute__((aligned(16))) float yb[16 * Y_STRIDE];   //  2,304 B
    __shared__ __attribute__((aligned(16))) float ob[160];
    __shared__ float lgt[16];

    const int tid  = threadIdx.x;
    const int b    = blockIdx.x;
    const int lane = tid & 63;
    const int w    = tid >> 6;            // wave 0..7
    const int l15  = lane & 15;
    const int lg4  = lane >> 4;           // quad 0..3
    const float* xg = x + (size_t)b * (512 * 32);

    // ---- stage 1: colsum partials (coalesced full read of x) ----
    {
        float4* scr = reinterpret_cast<float4*>(ypart);   // 8 KB scratch (fits)
        const float4* xg4 = reinterpret_cast<const float4*>(xg);
        float4 s4 = make_float4(0.f, 0.f, 0.f, 0.f);
        #pragma unroll
        for (int q = 0; q < 8; ++q) {     // idx&7 == tid&7: k-quad invariant
            const float4 v = xg4[tid + (q << 9)];
            s4.x += v.x; s4.y += v.y; s4.z += v.z; s4.w += v.w;
        }
        scr[tid] = s4;
    }

    // ---- stage 2: round-invariant x fragments into registers (bf16) ----
    short8 xA[4];        // PB B-frag: x[w*64+T*16+l15][lg4*8..+7]
    #pragma unroll
    for (int T = 0; T < 4; ++T) {
        const float* p = xg + ((w << 6) + (T << 4) + l15) * 32 + (lg4 << 3);
        const float4 a0 = *reinterpret_cast<const float4*>(p);
        const float4 a1 = *reinterpret_cast<const float4*>(p + 4);
        union { unsigned u[4]; short8 s8; } cv;
        cv.u[0] = cvt_pk_bf16(a0.x, a0.y);
        cv.u[1] = cvt_pk_bf16(a0.z, a0.w);
        cv.u[2] = cvt_pk_bf16(a1.x, a1.y);
        cv.u[3] = cvt_pk_bf16(a1.z, a1.w);
        xA[T] = cv.s8;
    }
    short8 xB[2][2];     // PA B-frag: B[i=(2w+ss)*32+lg4*8+q][k=l15+16t] = x[i][k]
    #pragma unroll
    for (int ss = 0; ss < 2; ++ss) {
        const int ib = ((w << 1) + ss) << 5;
        #pragma unroll
        for (int t = 0; t < 2; ++t) {
            const float* p = xg + (ib + (lg4 << 3)) * 32 + l15 + (t << 4);
            union { unsigned u[4]; short8 s8; } cv;
            cv.u[0] = cvt_pk_bf16(p[0 * 32], p[1 * 32]);
            cv.u[1] = cvt_pk_bf16(p[2 * 32], p[3 * 32]);
            cv.u[2] = cvt_pk_bf16(p[4 * 32], p[5 * 32]);
            cv.u[3] = cvt_pk_bf16(p[6 * 32], p[7 * 32]);
            xB[ss][t] = cv.s8;
        }
    }
    __syncthreads();

    // ---- y0 = 0.1 * colsum (c uniform = 1/J), f32-exact ----
    if (tid < 8) {
        const float4* scr = reinterpret_cast<const float4*>(ypart);
        float4 s = make_float4(0.f, 0.f, 0.f, 0.f);
        #pragma unroll
        for (int m = 0; m < 64; ++m) {
            const float4 v = scr[tid + (m << 3)];
            s.x += v.x; s.y += v.y; s.z += v.z; s.w += v.w;
        }
        s.x *= 0.1f; s.y *= 0.1f; s.z *= 0.1f; s.w *= 0.1f;
        #pragma unroll
        for (int j = 0; j < NJ; ++j)
            *reinterpret_cast<float4*>(&yb[j * Y_STRIDE + (tid << 2)]) = s;
    }
    __syncthreads();

    f32x4 blogA[4];      // blogT[j=lg4*4+rr][i=w*64+T*16+l15], persists all rounds
    #pragma unroll
    for (int T = 0; T < 4; ++T) blogA[T] = (f32x4){0.f, 0.f, 0.f, 0.f};

    for (int r = 0; r < 3; ++r) {
        // ===== S: s[j][d] = y[j] @ W_j(:,d); squash (r==2: logits) =====
        if (tid < 160) {
            const int j = tid >> 4, d = tid & 15;
            float s = 0.f;
            #pragma unroll
            for (int k4 = 0; k4 < 8; ++k4) {
                const float4 y4 = *reinterpret_cast<const float4*>(&yb[j * Y_STRIDE + (k4 << 2)]);
                const float* wp = W + (k4 << 2) * 160 + (j << 4) + d;
                s = fmaf(y4.x, wp[0],   s);
                s = fmaf(y4.y, wp[160], s);
                s = fmaf(y4.z, wp[320], s);
                s = fmaf(y4.w, wp[480], s);
            }
            float sq = s * s;
            sq += __shfl_xor(sq, 1); sq += __shfl_xor(sq, 2);
            sq += __shfl_xor(sq, 4); sq += __shfl_xor(sq, 8);
            const float scale = (sq / (1.f + sq)) / sqrtf(sq + 1e-7f);
            const float o_ = s * scale;
            if (r < 2) {
                ob[tid] = o_;
            } else {
                float ss = o_;
                ss += __shfl_xor(ss, 1); ss += __shfl_xor(ss, 2);
                ss += __shfl_xor(ss, 4); ss += __shfl_xor(ss, 8);
                if (d == 0) lgt[j] = ss;
            }
        }
        __syncthreads();
        if (r == 2) break;

        // ===== WT: wtb[j][k] = W_j-row(k) . o[j], rows j>=10 zeroed =====
        {
            const int j = tid >> 5, kk = tid & 31;    // tid<512 covers all 16x32
            const int jc = (j < NJ) ? j : (NJ - 1);
            const float zj = (j < NJ) ? 1.f : 0.f;
            const float4* W4 = reinterpret_cast<const float4*>(W + kk * 160 + (jc << 4));
            const float4* o4 = reinterpret_cast<const float4*>(&ob[jc << 4]);
            float s = 0.f;
            #pragma unroll
            for (int q = 0; q < 4; ++q) {
                const float4 wv = W4[q]; const float4 ov = o4[q];
                s += wv.x * ov.x + wv.y * ov.y + wv.z * ov.z + wv.w * ov.w;
            }
            wtb[j * WT_STRIDE + kk] = f2bf(s * zj);
        }
        __syncthreads();

        // ===== PB: blogA[T] += wt(A) @ xT(B); softmax_j -> cT bf16 =====
        {
            const short8 wf = *reinterpret_cast<const short8*>(&wtb[l15 * WT_STRIDE + (lg4 << 3)]);
            #pragma unroll
            for (int T = 0; T < 4; ++T)
                blogA[T] = __builtin_amdgcn_mfma_f32_16x16x32_bf16(wf, xA[T], blogA[T], 0, 0, 0);
            const int jb = lg4 << 2;
            #pragma unroll
            for (int T = 0; T < 4; ++T) {
                const f32x4 bv = blogA[T];
                const float v0 = (jb + 0 < NJ) ? bv[0] : -1e30f;
                const float v1 = (jb + 1 < NJ) ? bv[1] : -1e30f;
                const float v2 = (jb + 2 < NJ) ? bv[2] : -1e30f;
                const float v3 = (jb + 3 < NJ) ? bv[3] : -1e30f;
                float m = fmaxf(fmaxf(v0, v1), fmaxf(v2, v3));
                m = fmaxf(m, __shfl_xor(m, 16));
                m = fmaxf(m, __shfl_xor(m, 32));
                const float e0 = __expf(v0 - m), e1 = __expf(v1 - m);
                const float e2 = __expf(v2 - m), e3 = __expf(v3 - m);
                float ssum = e0 + e1 + e2 + e3;
                ssum += __shfl_xor(ssum, 16);
                ssum += __shfl_xor(ssum, 32);
                const float inv = 1.f / ssum;
                const int i = (w << 6) + (T << 4) + l15;   // global i of this column
                cT[(jb + 0) * CT_STRIDE + i] = f2bf(e0 * inv);
                cT[(jb + 1) * CT_STRIDE + i] = f2bf(e1 * inv);
                cT[(jb + 2) * CT_STRIDE + i] = f2bf(e2 * inv);
                cT[(jb + 3) * CT_STRIDE + i] = f2bf(e3 * inv);
            }
        }
        __syncthreads();

        // ===== PA: y partials, wave w does K-steps 2w, 2w+1 =====
        {
            f32x4 yf0 = (f32x4){0.f, 0.f, 0.f, 0.f};
            f32x4 yf1 = (f32x4){0.f, 0.f, 0.f, 0.f};
            #pragma unroll
            for (int ss = 0; ss < 2; ++ss) {
                const int sg = (w << 1) + ss;
                const short8 ca = *reinterpret_cast<const short8*>(
                    &cT[l15 * CT_STRIDE + (sg << 5) + (lg4 << 3)]);
                yf0 = __builtin_amdgcn_mfma_f32_16x16x32_bf16(ca, xB[ss][0], yf0, 0, 0, 0);
                yf1 = __builtin_amdgcn_mfma_f32_16x16x32_bf16(ca, xB[ss][1], yf1, 0, 0, 0);
            }
            #pragma unroll
            for (int rr = 0; rr < 4; ++rr) {
                ypart[w * YP_WS + ((lg4 << 2) + rr) * Y_STRIDE + l15]      = yf0[rr];
                ypart[w * YP_WS + ((lg4 << 2) + rr) * Y_STRIDE + 16 + l15] = yf1[rr];
            }
        }
        __syncthreads();

        // ===== reduce 8-wave partials -> yb =====
        {
            const int j = tid >> 5, k = tid & 31;     // tid<512 covers 16x32
            float s = 0.f;
            #pragma unroll
            for (int ww = 0; ww < 8; ++ww) s += ypart[ww * YP_WS + j * Y_STRIDE + k];
            yb[j * Y_STRIDE + k] = s;
        }
        __syncthreads();
    }

    // ---- final softmax over j, write out[b][0..9] ----
    if (tid < NJ) {
        float m = -1e30f;
        #pragma unroll
        for (int j = 0; j < NJ; ++j) m = fmaxf(m, lgt[j]);
        float sum = 0.f;
        #pragma unroll
        for (int j = 0; j < NJ; ++j) sum += __expf(lgt[j] - m);
        out[b * NJ + tid] = __expf(lgt[tid] - m) / sum;
    }
}

extern "C" void kernel_launch(void* const* d_in, const int* in_sizes, int n_in,
                              void* d_out, int out_size, void* d_ws, size_t ws_size,
                              hipStream_t stream) {
    (void)in_sizes; (void)n_in; (void)d_ws; (void)ws_size; (void)out_size;
    const float* x = (const float*)d_in[0];
    const float* W = (const float*)d_in[1];
    float* out = (float*)d_out;
    hipLaunchKernelGGL(capsnet_kernel, dim3(512), dim3(NT), 0, stream, x, W, out);
}